// Round 1
// baseline (357.925 us; speedup 1.0000x reference)
//
#include <hip/hip_runtime.h>
#include <math.h>

// Problem constants
#define MDIM 2048
#define D1C  128
#define D2C  16
#define NQC  32
#define NKC  128
#define HC   8
#define DHC  16
#define CC   64

// ---------------------------------------------------------------------------
// Kernel 1: LayerNorm(ql) @ Wq -> qbuf ; LayerNorm(cl) @ {Wk,Wv} -> kbuf,vbuf
// grid: 256 blocks x 8 rows, 256 threads
// ---------------------------------------------------------------------------
__global__ __launch_bounds__(256) void ln_proj_kernel(
    const float* __restrict__ ql, const float* __restrict__ cl,
    const float* __restrict__ Wq, const float* __restrict__ Wk,
    const float* __restrict__ Wv,
    float* __restrict__ qbuf, float* __restrict__ kbuf, float* __restrict__ vbuf)
{
    __shared__ float ldsQ[8 * 128];
    __shared__ float ldsC[8 * 128];
    const int tid = threadIdx.x;
    const int rg = tid >> 5;        // row in block 0..7
    const int t  = tid & 31;        // lane in row-group
    const int m  = blockIdx.x * 8 + rg;

    // --- LayerNorm both inputs ---
    const float4 xq = reinterpret_cast<const float4*>(ql)[m * 32 + t];
    const float4 xc = reinterpret_cast<const float4*>(cl)[m * 32 + t];
    float sQ  = xq.x + xq.y + xq.z + xq.w;
    float sqQ = xq.x*xq.x + xq.y*xq.y + xq.z*xq.z + xq.w*xq.w;
    float sC  = xc.x + xc.y + xc.z + xc.w;
    float sqC = xc.x*xc.x + xc.y*xc.y + xc.z*xc.z + xc.w*xc.w;
    #pragma unroll
    for (int msk = 16; msk; msk >>= 1) {
        sQ  += __shfl_xor(sQ,  msk);
        sqQ += __shfl_xor(sqQ, msk);
        sC  += __shfl_xor(sC,  msk);
        sqC += __shfl_xor(sqC, msk);
    }
    const float muQ = sQ * (1.0f / 128.0f);
    const float rsQ = rsqrtf(sqQ * (1.0f / 128.0f) - muQ * muQ + 1e-5f);
    const float muC = sC * (1.0f / 128.0f);
    const float rsC = rsqrtf(sqC * (1.0f / 128.0f) - muC * muC + 1e-5f);

    reinterpret_cast<float4*>(ldsQ)[rg * 32 + t] =
        make_float4((xq.x - muQ) * rsQ, (xq.y - muQ) * rsQ,
                    (xq.z - muQ) * rsQ, (xq.w - muQ) * rsQ);
    reinterpret_cast<float4*>(ldsC)[rg * 32 + t] =
        make_float4((xc.x - muC) * rsC, (xc.y - muC) * rsC,
                    (xc.z - muC) * rsC, (xc.w - muC) * rsC);
    __syncthreads();

    // --- 3 projections: each thread computes 4 rows x 1 col per matrix ---
    const int j   = tid & 127;
    const int rg2 = tid >> 7;       // 0/1
    const int r0  = rg2 * 4;
    float aq[4] = {0,0,0,0}, ak[4] = {0,0,0,0}, av[4] = {0,0,0,0};
    const float4* lq4 = reinterpret_cast<const float4*>(ldsQ);
    const float4* lc4 = reinterpret_cast<const float4*>(ldsC);
    for (int i4 = 0; i4 < 32; ++i4) {
        const int i = i4 * 4;
        const float wq0 = Wq[(i+0)*128 + j], wq1 = Wq[(i+1)*128 + j];
        const float wq2 = Wq[(i+2)*128 + j], wq3 = Wq[(i+3)*128 + j];
        const float wk0 = Wk[(i+0)*128 + j], wk1 = Wk[(i+1)*128 + j];
        const float wk2 = Wk[(i+2)*128 + j], wk3 = Wk[(i+3)*128 + j];
        const float wv0 = Wv[(i+0)*128 + j], wv1 = Wv[(i+1)*128 + j];
        const float wv2 = Wv[(i+2)*128 + j], wv3 = Wv[(i+3)*128 + j];
        #pragma unroll
        for (int rr = 0; rr < 4; ++rr) {
            const float4 x = lq4[(r0 + rr) * 32 + i4];
            aq[rr] = fmaf(x.x, wq0, fmaf(x.y, wq1, fmaf(x.z, wq2, fmaf(x.w, wq3, aq[rr]))));
            const float4 y = lc4[(r0 + rr) * 32 + i4];
            ak[rr] = fmaf(y.x, wk0, fmaf(y.y, wk1, fmaf(y.z, wk2, fmaf(y.w, wk3, ak[rr]))));
            av[rr] = fmaf(y.x, wv0, fmaf(y.y, wv1, fmaf(y.z, wv2, fmaf(y.w, wv3, av[rr]))));
        }
    }
    #pragma unroll
    for (int rr = 0; rr < 4; ++rr) {
        const int mm = blockIdx.x * 8 + r0 + rr;
        qbuf[(size_t)mm * 128 + j] = aq[rr];
        kbuf[(size_t)mm * 128 + j] = ak[rr];
        vbuf[(size_t)mm * 128 + j] = av[rr];
    }
}

// ---------------------------------------------------------------------------
// Kernel 2: bias[c][h][q][k] = sum_d2 plm[qi,ki,d2] * Wb[d2,h]
// grid: C*NQ = 2048 blocks, 128 threads (one per k)
// ---------------------------------------------------------------------------
__global__ __launch_bounds__(128) void bias_kernel(
    const float* __restrict__ plm, const float* __restrict__ Wb,
    const int* __restrict__ query_idx, const int* __restrict__ key_idx,
    float* __restrict__ biasBuf)
{
    __shared__ float wb[128];
    const int tid = threadIdx.x;
    wb[tid] = Wb[tid];              // 16x8 = 128 floats
    const int cq = blockIdx.x;
    const int c = cq >> 5, q = cq & 31;
    const int qi = query_idx[cq];
    const int ki = key_idx[c * 128 + tid];
    __syncthreads();

    const size_t base = ((size_t)qi * 2048 + (size_t)ki) * 16;
    const float4* p4 = reinterpret_cast<const float4*>(plm + base);
    const float4 r0 = p4[0], r1 = p4[1], r2 = p4[2], r3 = p4[3];
    const float rowv[16] = { r0.x, r0.y, r0.z, r0.w, r1.x, r1.y, r1.z, r1.w,
                             r2.x, r2.y, r2.z, r2.w, r3.x, r3.y, r3.z, r3.w };
    #pragma unroll
    for (int h = 0; h < 8; ++h) {
        float acc = 0.0f;
        #pragma unroll
        for (int d = 0; d < 16; ++d) acc = fmaf(rowv[d], wb[d * 8 + h], acc);
        biasBuf[((size_t)((c * 8 + h) * 32 + q)) * 128 + tid] = acc;
    }
}

// ---------------------------------------------------------------------------
// Kernel 3: windowed attention per (c,h). 256 threads = 32 q x 8 ks.
// Each thread handles keys k = ks + 8*j, j=0..15. LDS rows padded to 20
// floats so the 8 ks-lanes hit 8 distinct banks (conflict-free b128 reads).
// ---------------------------------------------------------------------------
__global__ __launch_bounds__(256) void attn_kernel(
    const float* __restrict__ qbuf, const float* __restrict__ kbuf,
    const float* __restrict__ vbuf, const float* __restrict__ biasBuf,
    const int* __restrict__ query_idx, const int* __restrict__ query_mask,
    const int* __restrict__ key_idx, const int* __restrict__ key_mask,
    float* __restrict__ obuf)
{
    __shared__ float kw[128 * 20];
    __shared__ float vw[128 * 20];
    const int bid = blockIdx.x;
    const int c = bid >> 3, h = bid & 7;
    const int tid = threadIdx.x;

    // stage K,V head-slices into LDS (row stride 20 floats)
    for (int idx = tid; idx < 512; idx += 256) {
        const int k = idx >> 2, f = idx & 3;
        const int ki = key_idx[c * 128 + k];
        const float4 kv = reinterpret_cast<const float4*>(
            kbuf + (size_t)ki * 128 + h * 16)[f];
        *reinterpret_cast<float4*>(&kw[k * 20 + f * 4]) = kv;
        const float4 vv = reinterpret_cast<const float4*>(
            vbuf + (size_t)ki * 128 + h * 16)[f];
        *reinterpret_cast<float4*>(&vw[k * 20 + f * 4]) = vv;
    }

    const int q = tid >> 3, ks = tid & 7;
    const int qrow = query_idx[c * 32 + q];
    float qr[16];
    {
        const float4* qb4 = reinterpret_cast<const float4*>(
            qbuf + (size_t)qrow * 128 + h * 16);
        #pragma unroll
        for (int f = 0; f < 4; ++f) {
            const float4 v = qb4[f];
            qr[f*4+0] = v.x; qr[f*4+1] = v.y; qr[f*4+2] = v.z; qr[f*4+3] = v.w;
        }
    }
    __syncthreads();

    const float* bias = biasBuf + ((size_t)((c * 8 + h) * 32 + q)) * 128;
    float sarr[16];
    float mloc = -1e30f;
    #pragma unroll
    for (int j = 0; j < 16; ++j) {
        const int k = ks + 8 * j;
        const float* kr = &kw[k * 20];
        float dot = 0.0f;
        #pragma unroll
        for (int d = 0; d < 16; ++d) dot = fmaf(qr[d], kr[d], dot);
        float sc = fmaf(dot, 0.25f, bias[k]);
        sc = key_mask[c * 128 + k] ? sc : -1e30f;
        sarr[j] = sc;
        mloc = fmaxf(mloc, sc);
    }
    #pragma unroll
    for (int msk = 1; msk < 8; msk <<= 1) mloc = fmaxf(mloc, __shfl_xor(mloc, msk));

    float l = 0.0f;
    float p[16];
    #pragma unroll
    for (int j = 0; j < 16; ++j) { p[j] = __expf(sarr[j] - mloc); l += p[j]; }
    #pragma unroll
    for (int msk = 1; msk < 8; msk <<= 1) l += __shfl_xor(l, msk);

    float acc[16];
    #pragma unroll
    for (int d = 0; d < 16; ++d) acc[d] = 0.0f;
    #pragma unroll
    for (int j = 0; j < 16; ++j) {
        const int k = ks + 8 * j;
        const float* vr = &vw[k * 20];
        const float pj = p[j];
        #pragma unroll
        for (int d = 0; d < 16; ++d) acc[d] = fmaf(pj, vr[d], acc[d]);
    }
    #pragma unroll
    for (int msk = 1; msk < 8; msk <<= 1) {
        #pragma unroll
        for (int d = 0; d < 16; ++d) acc[d] += __shfl_xor(acc[d], msk);
    }
    if (ks == 0) {
        const float scale = (1.0f / l) * (float)query_mask[c * 32 + q];
        float4* ob = reinterpret_cast<float4*>(
            obuf + (size_t)(c * 32 + q) * 128 + h * 16);
        #pragma unroll
        for (int f = 0; f < 4; ++f)
            ob[f] = make_float4(acc[f*4+0]*scale, acc[f*4+1]*scale,
                                acc[f*4+2]*scale, acc[f*4+3]*scale);
    }
}

// ---------------------------------------------------------------------------
// Kernel 4: out = ql + obuf @ Wo.  256 blocks x 8 rows, 256 threads.
// ---------------------------------------------------------------------------
__global__ __launch_bounds__(256) void out_proj_kernel(
    const float* __restrict__ obuf, const float* __restrict__ Wo,
    const float* __restrict__ ql, float* __restrict__ out)
{
    __shared__ float ldsO[8 * 128];
    const int tid = threadIdx.x;
    reinterpret_cast<float4*>(ldsO)[tid] =
        reinterpret_cast<const float4*>(obuf)[blockIdx.x * 256 + tid];
    __syncthreads();

    const int j   = tid & 127;
    const int rg2 = tid >> 7;
    const int r0  = rg2 * 4;
    float acc[4] = {0,0,0,0};
    const float4* lo4 = reinterpret_cast<const float4*>(ldsO);
    for (int i4 = 0; i4 < 32; ++i4) {
        const int i = i4 * 4;
        const float w0 = Wo[(i+0)*128 + j], w1 = Wo[(i+1)*128 + j];
        const float w2 = Wo[(i+2)*128 + j], w3 = Wo[(i+3)*128 + j];
        #pragma unroll
        for (int rr = 0; rr < 4; ++rr) {
            const float4 x = lo4[(r0 + rr) * 32 + i4];
            acc[rr] = fmaf(x.x, w0, fmaf(x.y, w1, fmaf(x.z, w2, fmaf(x.w, w3, acc[rr]))));
        }
    }
    #pragma unroll
    for (int rr = 0; rr < 4; ++rr) {
        const int m = blockIdx.x * 8 + r0 + rr;
        out[(size_t)m * 128 + j] = ql[(size_t)m * 128 + j] + acc[rr];
    }
}

// ---------------------------------------------------------------------------
extern "C" void kernel_launch(void* const* d_in, const int* in_sizes, int n_in,
                              void* d_out, int out_size, void* d_ws, size_t ws_size,
                              hipStream_t stream) {
    const float* ql  = (const float*)d_in[0];
    const float* cl  = (const float*)d_in[1];
    const float* plm = (const float*)d_in[2];
    const float* Wq  = (const float*)d_in[3];
    const float* Wk  = (const float*)d_in[4];
    const float* Wv  = (const float*)d_in[5];
    const float* Wb  = (const float*)d_in[6];
    const float* Wo  = (const float*)d_in[7];
    const int* query_idx  = (const int*)d_in[8];
    const int* query_mask = (const int*)d_in[9];
    const int* key_idx    = (const int*)d_in[10];
    const int* key_mask   = (const int*)d_in[11];
    float* out = (float*)d_out;

    float* ws = (float*)d_ws;
    float* qbuf    = ws;                    // 2048*128
    float* kbuf    = ws + 262144;           // 2048*128
    float* vbuf    = ws + 524288;           // 2048*128
    float* obuf    = ws + 786432;           // 2048*128
    float* biasBuf = ws + 1048576;          // 64*8*32*128 = 2097152

    ln_proj_kernel<<<256, 256, 0, stream>>>(ql, cl, Wq, Wk, Wv, qbuf, kbuf, vbuf);
    bias_kernel<<<2048, 128, 0, stream>>>(plm, Wb, query_idx, key_idx, biasBuf);
    attn_kernel<<<512, 256, 0, stream>>>(qbuf, kbuf, vbuf, biasBuf,
                                         query_idx, query_mask, key_idx, key_mask,
                                         obuf);
    out_proj_kernel<<<256, 256, 0, stream>>>(obuf, Wo, ql, out);
}